// Round 1
// 509.292 us; speedup vs baseline: 1.1785x; 1.1785x over previous
//
#include <hip/hip_runtime.h>
#include <cstdint>

// ============================================================================
// QunatEncoderBlock: windowed attention block with int8 fake-quant.
// All qlinear / QK^T / PV matmuls are EXACT in int8xint8->int32 (MFMA i8).
// Rel-pos bias via bf16 MFMA with hi/lo split tables (error ~2^-18).
// R1: k_attn restructured to 1-wave/1-tile blocks (grid 13x1200, 64 thr).
//     Waves were fully independent already; 256-thread blocks only created
//     a VGPR-bound occupancy cap (140 VGPR -> 8 waves/CU) + tile-count
//     imbalance. Now: <=128 VGPR via launch_bounds(64,4) + packed ckh/ckw,
//     8.6KB LDS/block -> 16 waves/CU, perfect balance, t-fastest grid for
//     K/V L2 reuse. relS stride 64->66 kills 4-way store bank conflict.
// ============================================================================

typedef int   v4i __attribute__((ext_vector_type(4)));
typedef float v4f __attribute__((ext_vector_type(4)));
typedef short v8s __attribute__((ext_vector_type(8)));
typedef int8_t i8;

__device__ __forceinline__ i8 satq(float x) {   // x already scale-divided
  float q = rintf(x);
  q = fminf(127.f, fmaxf(-128.f, q));
  return (i8)(int)q;
}

__device__ __forceinline__ void gload16(const i8* g, i8* l) {
  __builtin_amdgcn_global_load_lds((const __attribute__((address_space(1))) void*)g,
                                   (__attribute__((address_space(3))) void*)l, 16, 0, 0);
}

__device__ __forceinline__ int pack4(const i8* q) {
  return ((int)(unsigned char)q[0]) | ((int)(unsigned char)q[1] << 8) |
         ((int)(unsigned char)q[2] << 16) | ((int)(unsigned char)q[3] << 24);
}

// ---------------------------------------------------------------------------
// weight fake-quant -> int8, 16 elements/thread
// ---------------------------------------------------------------------------
__global__ __launch_bounds__(256) void k_wquant(const float* __restrict__ w,
                                                i8* __restrict__ o, int n16,
                                                const float* __restrict__ wsc, int sidx) {
  int i = blockIdx.x * 256 + threadIdx.x;
  if (i >= n16) return;
  float inv = 1.0f / wsc[sidx];
  const float4* src = (const float4*)w + (size_t)i * 4;
  i8 buf[16];
#pragma unroll
  for (int t = 0; t < 4; t++) {
    float4 f = src[t];
    buf[t*4+0] = satq(f.x * inv); buf[t*4+1] = satq(f.y * inv);
    buf[t*4+2] = satq(f.z * inv); buf[t*4+3] = satq(f.w * inv);
  }
  *(v4i*)(o + (size_t)i * 16) = *(v4i*)buf;
}

// ---------------------------------------------------------------------------
// pack rel-pos tables for bf16 MFMA B-operand, hi/lo split.
// chunk c = (tb*2+nt)*4 + ks*2 + p ; frag = TB[c*512 + lane*8 .. +8]
// B[n][k] = table[n*64+k] (n<27 else 0), n = nt*16+(lane&15), k = ks*32+(lane>>4)*8+j
// ---------------------------------------------------------------------------
__global__ __launch_bounds__(256) void k_relpack(const float* __restrict__ rph,
    const float* __restrict__ rpw, short* __restrict__ TB) {
  int g = blockIdx.x * 256 + threadIdx.x;
  if (g >= 1024) return;
  int lane = g & 63, c = g >> 6;
  int p = c & 1, ks = (c >> 1) & 1, nt = (c >> 2) & 1, tb = c >> 3;
  const float* src = tb ? rpw : rph;
  int n = nt * 16 + (lane & 15);
  int k0 = ks * 32 + (lane >> 4) * 8;
  short outv[8];
#pragma unroll
  for (int j = 0; j < 8; j++) {
    float v = (n < 27) ? src[n * 64 + k0 + j] : 0.f;
    unsigned u = __float_as_uint(v);
    unsigned hi = (u + 0x7fffu + ((u >> 16) & 1u)) >> 16;
    if (p == 0) outv[j] = (short)hi;
    else {
      float lof = v - __uint_as_float(hi << 16);
      unsigned ul = __float_as_uint(lof);
      outv[j] = (short)((ul + 0x7fffu + ((ul >> 16) & 1u)) >> 16);
    }
  }
  *(v8s*)(TB + (size_t)c * 512 + lane * 8) = *(v8s*)outv;
}

// ---------------------------------------------------------------------------
// LN1: wave per window-token (pad 64->70, 5x5 windows of 14x14), quant a_s[4]
// ---------------------------------------------------------------------------
__global__ __launch_bounds__(256) void k_ln1(const float* __restrict__ x,
    const float* __restrict__ w, const float* __restrict__ b,
    const float* __restrict__ as, i8* __restrict__ outq) {
  int wt = blockIdx.x * 4 + (threadIdx.x >> 6);
  int lane = threadIdx.x & 63;
  int win = wt / 196, tok = wt - win * 196;
  int bb = win / 25, wrem = win - bb * 25, wh = wrem / 5, ww = wrem - wh * 5;
  int r = tok / 14, c = tok - r * 14;
  int y = wh * 14 + r, xx = ww * 14 + c;
  i8* dst = outq + (size_t)wt * 768 + lane * 12;
  if (y >= 64 || xx >= 64) {
    ((int*)dst)[0] = 0; ((int*)dst)[1] = 0; ((int*)dst)[2] = 0;
    return;
  }
  const float* row = x + (((size_t)bb * 64 + y) * 64 + xx) * 768 + lane * 12;
  float v[12];
  *(float4*)(v)     = *(const float4*)(row);
  *(float4*)(v + 4) = *(const float4*)(row + 4);
  *(float4*)(v + 8) = *(const float4*)(row + 8);
  float s = 0.f, ss = 0.f;
#pragma unroll
  for (int j = 0; j < 12; j++) { s += v[j]; ss += v[j] * v[j]; }
#pragma unroll
  for (int off = 1; off < 64; off <<= 1) { s += __shfl_xor(s, off); ss += __shfl_xor(ss, off); }
  float mu = s * (1.0f / 768.0f);
  float var = ss * (1.0f / 768.0f) - mu * mu;
  float rstd = 1.0f / sqrtf(var + 1e-6f);
  float inv = 1.0f / as[4];
  float wv[12], bv[12];
  *(float4*)(wv)     = *(const float4*)(w + lane * 12);
  *(float4*)(wv + 4) = *(const float4*)(w + lane * 12 + 4);
  *(float4*)(wv + 8) = *(const float4*)(w + lane * 12 + 8);
  *(float4*)(bv)     = *(const float4*)(b + lane * 12);
  *(float4*)(bv + 4) = *(const float4*)(b + lane * 12 + 4);
  *(float4*)(bv + 8) = *(const float4*)(b + lane * 12 + 8);
  i8 q[12];
#pragma unroll
  for (int j = 0; j < 12; j++) q[j] = satq(((v[j] - mu) * rstd * wv[j] + bv[j]) * inv);
  ((int*)dst)[0] = pack4(q); ((int*)dst)[1] = pack4(q + 4); ((int*)dst)[2] = pack4(q + 8);
}

// ---------------------------------------------------------------------------
// LN2: wave per token, quant a_s[6]
// ---------------------------------------------------------------------------
__global__ __launch_bounds__(256) void k_ln2(const float* __restrict__ x2,
    const float* __restrict__ w, const float* __restrict__ b,
    const float* __restrict__ as, i8* __restrict__ outq) {
  int tokg = blockIdx.x * 4 + (threadIdx.x >> 6);
  int lane = threadIdx.x & 63;
  const float* row = x2 + (size_t)tokg * 768 + lane * 12;
  float v[12];
  *(float4*)(v)     = *(const float4*)(row);
  *(float4*)(v + 4) = *(const float4*)(row + 4);
  *(float4*)(v + 8) = *(const float4*)(row + 8);
  float s = 0.f, ss = 0.f;
#pragma unroll
  for (int j = 0; j < 12; j++) { s += v[j]; ss += v[j] * v[j]; }
#pragma unroll
  for (int off = 1; off < 64; off <<= 1) { s += __shfl_xor(s, off); ss += __shfl_xor(ss, off); }
  float mu = s * (1.0f / 768.0f);
  float var = ss * (1.0f / 768.0f) - mu * mu;
  float rstd = 1.0f / sqrtf(var + 1e-6f);
  float inv = 1.0f / as[6];
  float wv[12], bv[12];
  *(float4*)(wv)     = *(const float4*)(w + lane * 12);
  *(float4*)(wv + 4) = *(const float4*)(w + lane * 12 + 4);
  *(float4*)(wv + 8) = *(const float4*)(w + lane * 12 + 8);
  *(float4*)(bv)     = *(const float4*)(b + lane * 12);
  *(float4*)(bv + 4) = *(const float4*)(b + lane * 12 + 4);
  *(float4*)(bv + 8) = *(const float4*)(b + lane * 12 + 8);
  i8* dst = outq + (size_t)tokg * 768 + lane * 12;
  i8 q[12];
#pragma unroll
  for (int j = 0; j < 12; j++) q[j] = satq(((v[j] - mu) * rstd * wv[j] + bv[j]) * inv);
  ((int*)dst)[0] = pack4(q); ((int*)dst)[1] = pack4(q + 4); ((int*)dst)[2] = pack4(q + 8);
}

// ---------------------------------------------------------------------------
// int8 GEMM: C[M,N] = A[M,K] x B[N,K]^T, 128x128 tile, BK=64, m97 structure
// with global_load_lds width-16 staging. N%128==0, K%64==0, M%4==0.
// ---------------------------------------------------------------------------
template <class Epi>
__global__ __launch_bounds__(256) void k_gemm(const i8* __restrict__ A, const i8* __restrict__ B,
                                              int M, int N, int K, Epi epi) {
  __shared__ __align__(16) i8 As[128 * 64];
  __shared__ __align__(16) i8 Bs[128 * 64];
  const int tid = threadIdx.x;
  const int lane = tid & 63, wave = tid >> 6;
  const int quad = lane >> 4, lc = lane & 15;
  const int wr = wave >> 1, wc = wave & 1;
  const long bm = (long)blockIdx.y * 128, bn = (long)blockIdx.x * 128;
  const v4i vz = {0, 0, 0, 0};
  v4i acc[4][4];
#pragma unroll
  for (int i = 0; i < 4; i++)
#pragma unroll
    for (int j = 0; j < 4; j++) acc[i][j] = vz;

  const int r0 = tid >> 2, c0 = tid & 3;
  long rA0 = bm + r0;      if (rA0 >= M) rA0 = 0;
  long rA1 = bm + r0 + 64; if (rA1 >= M) rA1 = 0;
  const i8* pA0 = A + rA0 * (size_t)K + c0 * 16;
  const i8* pA1 = A + rA1 * (size_t)K + c0 * 16;
  const i8* pB0 = B + (bn + r0)      * (size_t)K + c0 * 16;
  const i8* pB1 = B + (bn + r0 + 64) * (size_t)K + c0 * 16;
  i8* lA0 = As + tid * 16;
  i8* lA1 = As + 4096 + tid * 16;
  i8* lB0 = Bs + tid * 16;
  i8* lB1 = Bs + 4096 + tid * 16;

  for (int kt = 0; kt < K; kt += 64) {
    __syncthreads();
    gload16(pA0, lA0); gload16(pA1, lA1);
    gload16(pB0, lB0); gload16(pB1, lB1);
    pA0 += 64; pA1 += 64; pB0 += 64; pB1 += 64;
    __syncthreads();
    v4i af[4], bf[4];
#pragma unroll
    for (int i = 0; i < 4; i++) af[i] = *(const v4i*)(As + (wr * 64 + i * 16 + lc) * 64 + quad * 16);
#pragma unroll
    for (int j = 0; j < 4; j++) bf[j] = *(const v4i*)(Bs + (wc * 64 + j * 16 + lc) * 64 + quad * 16);
#pragma unroll
    for (int i = 0; i < 4; i++)
#pragma unroll
      for (int j = 0; j < 4; j++)
        acc[i][j] = __builtin_amdgcn_mfma_i32_16x16x64_i8(af[i], bf[j], acc[i][j], 0, 0, 0);
  }
  Epi e = epi;
  e.init();
#pragma unroll
  for (int i = 0; i < 4; i++) {
    int gm0 = (int)bm + wr * 64 + i * 16 + quad * 4;   // C/D: row=quad*4+reg, col=lc
#pragma unroll
    for (int j = 0; j < 4; j++) {
      int gn = (int)bn + wc * 64 + j * 16 + lc;
      if (gm0 < M) e.store4(acc[i][j], gm0, gn);
    }
  }
}

// -------- epilogues (store4: 4 consecutive rows m0..m0+3, all < M) --------
struct EpiQKV {   // split into q,k (token-major) and v^T (ch-major, stride 256)
  const float* as; const float* wsc; const float* bias;
  i8 *qq, *kq, *vt;
  float sab, invq, invk, invv;
  __device__ void init() {
    sab = as[4] * wsc[0]; invq = 1.f / as[0]; invk = 1.f / as[1]; invv = 1.f / as[2];
  }
  __device__ void store4(const v4i a, int m0, int n) {
    int t = n / 768, rem = n - t * 768;
    int head = rem >> 6, ch = rem & 63;
    int win = m0 / 196, tok0 = m0 - win * 196;   // m0%4==0, 196%4==0: no window straddle
    size_t bh = (size_t)win * 12 + head;
    float bv = bias[n];
    if (t == 2) {
      i8 q[4];
#pragma unroll
      for (int r = 0; r < 4; r++) q[r] = satq(((float)a[r] * sab + bv) * invv);
      *(int*)(vt + (bh * 64 + ch) * 256 + tok0) = pack4(q);
    } else {
      float inv = (t == 0) ? invq : invk;
      i8* dst = (t == 0 ? qq : kq) + (bh * 196 + tok0) * 64 + ch;
#pragma unroll
      for (int r = 0; r < 4; r++) dst[(size_t)r * 64] = satq(((float)a[r] * sab + bv) * inv);
    }
  }
};

struct EpiProj {  // window reverse + unpad + shortcut add -> x2 (in d_out)
  const float* as; const float* wsc; const float* bias; const float* x0; float* out;
  float sab;
  __device__ void init() { sab = as[5] * wsc[1]; }
  __device__ void store4(const v4i a, int m0, int n) {
    int win = m0 / 196, tok0 = m0 - win * 196;
    int bb = win / 25, wrem = win - bb * 25, wh = wrem / 5, ww = wrem - wh * 5;
    float bv = bias[n];
#pragma unroll
    for (int r = 0; r < 4; r++) {
      int tok = tok0 + r;
      int rr = tok / 14, cc = tok - rr * 14;
      int y = wh * 14 + rr, xx = ww * 14 + cc;
      if (y < 64 && xx < 64) {
        size_t o = (((size_t)bb * 64 + y) * 64 + xx) * 768 + n;
        out[o] = (float)a[r] * sab + bv + x0[o];
      }
    }
  }
};

struct EpiLin1 {  // bias + exact gelu + quant a_s[7]
  const float* as; const float* wsc; const float* bias; i8* outq;
  float sab, invg;
  __device__ void init() { sab = as[6] * wsc[2]; invg = 1.f / as[7]; }
  __device__ void store4(const v4i a, int m0, int n) {
    float bv = bias[n];
#pragma unroll
    for (int r = 0; r < 4; r++) {
      float v = (float)a[r] * sab + bv;
      float g = 0.5f * v * (1.0f + erff(v * 0.70710678118654752f));
      outq[(size_t)(m0 + r) * 3072 + n] = satq(g * invg);
    }
  }
};

struct EpiLin2 {  // bias + residual add into d_out
  const float* as; const float* wsc; const float* bias; float* out;
  float sab;
  __device__ void init() { sab = as[7] * wsc[3]; }
  __device__ void store4(const v4i a, int m0, int n) {
    float bv = bias[n];
#pragma unroll
    for (int r = 0; r < 4; r++) {
      size_t o = (size_t)(m0 + r) * 768 + n;
      out[o] += (float)a[r] * sab + bv;
    }
  }
};

// ---------------------------------------------------------------------------
// attention: ONE WAVE per (win*12+head, 16-row tile). Grid (13, 1200), 64 thr.
// No inter-wave communication; 8.6KB LDS + <=128 VGPR -> 16 waves/CU.
// Rel-pos bias via bf16 MFMA (hi/lo split tables). QK^T & PV via i8 MFMA.
// ---------------------------------------------------------------------------
__global__ __launch_bounds__(64, 4) void k_attn(const i8* __restrict__ qq, const i8* __restrict__ kq,
    const i8* __restrict__ vt, const short* __restrict__ TB,
    const float* __restrict__ as, i8* __restrict__ outq) {
  __shared__ __align__(16) i8 Ps[16 * 272];       // this wave's P tile
  __shared__ float relS[16][66];                  // rel bias [row][d(h)|32+d(w)], stride 66: 2-way banks
  const int t = blockIdx.x, bh = blockIdx.y;
  const int win = bh / 12, head = bh - win * 12;
  const int lane = threadIdx.x;
  const int quad = lane >> 4, lc = lane & 15;
  const float s0 = as[0];
  const float ssc = s0 * as[1] * 0.125f;
  const float invs3 = 1.0f / as[3];
  const float oscale = as[2] * as[3] / as[5];

  // zero pad cols [192,256)
  for (int idx = lane; idx < 256; idx += 64)
    *(int*)(Ps + (idx >> 4) * 272 + 192 + (idx & 15) * 4) = 0;

  // per-lane col decomposition, byte-packed (kh,kw <= 13): saves ~18 VGPR
  unsigned ckhp[4] = {0, 0, 0, 0}, ckwp[4] = {0, 0, 0, 0};
#pragma unroll
  for (int f = 0; f < 13; f++) {
    int col = f * 16 + lc; if (col > 195) col = 195;
    int kh = col / 14, kw = col - kh * 14;
    ckhp[f >> 2] |= (unsigned)kh << ((f & 3) * 8);
    ckwp[f >> 2] |= (unsigned)kw << ((f & 3) * 8);
  }

  const v8s* TBv = (const v8s*)TB;
  const v4i vz = {0, 0, 0, 0};

  // ---- rel-pos bias via bf16 MFMA ----
  {
    int arow = t * 16 + lc; if (arow > 195) arow = 195;
    const i8* qrow = qq + ((size_t)bh * 196 + arow) * 64;
    v8s af[2];
#pragma unroll
    for (int ks = 0; ks < 2; ks++) {
      const i8* p = qrow + ks * 32 + quad * 8;
#pragma unroll
      for (int j = 0; j < 8; j++)
        af[ks][j] = (short)(__float_as_uint((float)p[j]) >> 16);  // exact int->bf16
    }
    v4f rh0 = {0,0,0,0}, rh1 = {0,0,0,0}, rw0 = {0,0,0,0}, rw1 = {0,0,0,0};
#pragma unroll
    for (int ks = 0; ks < 2; ks++)
#pragma unroll
      for (int p2 = 0; p2 < 2; p2++) {
        rh0 = __builtin_amdgcn_mfma_f32_16x16x32_bf16(af[ks], TBv[(0*4 + ks*2 + p2)*64 + lane], rh0, 0, 0, 0);
        rh1 = __builtin_amdgcn_mfma_f32_16x16x32_bf16(af[ks], TBv[(1*4 + ks*2 + p2)*64 + lane], rh1, 0, 0, 0);
        rw0 = __builtin_amdgcn_mfma_f32_16x16x32_bf16(af[ks], TBv[(2*4 + ks*2 + p2)*64 + lane], rw0, 0, 0, 0);
        rw1 = __builtin_amdgcn_mfma_f32_16x16x32_bf16(af[ks], TBv[(3*4 + ks*2 + p2)*64 + lane], rw1, 0, 0, 0);
      }
#pragma unroll
    for (int r = 0; r < 4; r++) {
      int rl = quad * 4 + r;
      relS[rl][lc]      = rh0[r] * s0;
      relS[rl][16 + lc] = rh1[r] * s0;
      relS[rl][32 + lc] = rw0[r] * s0;
      relS[rl][48 + lc] = rw1[r] * s0;
    }
  }

  // ---- QK^T (int-exact) ----
  v4i aq = *(const v4i*)(qq + ((size_t)bh * 196 + t * 16 + lc) * 64 + quad * 16);
  v4i sacc[13];
#pragma unroll
  for (int f = 0; f < 13; f++) {
    v4i bk = *(const v4i*)(kq + ((size_t)bh * 196 + f * 16 + lc) * 64 + quad * 16);
    sacc[f] = __builtin_amdgcn_mfma_i32_16x16x64_i8(aq, bk, vz, 0, 0, 0);
  }

  // ---- softmax + P quant ----
#pragma unroll
  for (int r = 0; r < 4; r++) {
    int rl = quad * 4 + r;
    int row = t * 16 + rl;
    int qh = row / 14, qw = row - qh * 14;
    const float* rH = &relS[rl][13 + qh];        // rH[-kh]
    const float* rW = &relS[rl][32 + 13 + qw];   // rW[-kw]
    float L[13];
#pragma unroll
    for (int f = 0; f < 13; f++) {
      int kh = (int)((ckhp[f >> 2] >> ((f & 3) * 8)) & 0xffu);
      int kw = (int)((ckwp[f >> 2] >> ((f & 3) * 8)) & 0xffu);
      // cok = col<196  <=>  f<12 || lc<4  (compile-time for f<12 under unroll)
      L[f] = ((f < 12) | (lc < 4)) ? fmaf((float)sacc[f][r], ssc, rH[-kh] + rW[-kw]) : -1e30f;
    }
    float mx = L[0];
#pragma unroll
    for (int f = 1; f < 13; f++) mx = fmaxf(mx, L[f]);
#pragma unroll
    for (int off = 1; off < 16; off <<= 1) mx = fmaxf(mx, __shfl_xor(mx, off));
    float sum = 0.f;
#pragma unroll
    for (int f = 0; f < 13; f++) { float e = __expf(L[f] - mx); L[f] = e; sum += e; }
#pragma unroll
    for (int off = 1; off < 16; off <<= 1) sum += __shfl_xor(sum, off);
    float cq = (1.0f / sum) * invs3;
#pragma unroll
    for (int f = 0; f < 13; f++)
      Ps[rl * 272 + f * 16 + lc] = satq(L[f] * cq);
  }

  // ---- PV (int-exact) ----
  v4i oacc[4];
#pragma unroll
  for (int nt = 0; nt < 4; nt++) oacc[nt] = vz;
#pragma unroll
  for (int kc = 0; kc < 4; kc++) {
    v4i ap = *(const v4i*)(Ps + lc * 272 + kc * 64 + quad * 16);
#pragma unroll
    for (int nt = 0; nt < 4; nt++) {
      v4i bv = *(const v4i*)(vt + ((size_t)bh * 64 + nt * 16 + lc) * 256 + kc * 64 + quad * 16);
      oacc[nt] = __builtin_amdgcn_mfma_i32_16x16x64_i8(ap, bv, oacc[nt], 0, 0, 0);
    }
  }
#pragma unroll
  for (int nt = 0; nt < 4; nt++) {
    int ch = nt * 16 + lc;
#pragma unroll
    for (int r = 0; r < 4; r++) {
      int row = t * 16 + quad * 4 + r;
      if (row < 196)
        outq[((size_t)win * 196 + row) * 768 + head * 64 + ch] = satq((float)oacc[nt][r] * oscale);
    }
  }
}

// ---------------------------------------------------------------------------
extern "C" void kernel_launch(void* const* d_in, const int* in_sizes, int n_in,
                              void* d_out, int out_size, void* d_ws, size_t ws_size,
                              hipStream_t stream) {
  const float* x     = (const float*)d_in[0];
  const float* ln1w  = (const float*)d_in[1];
  const float* ln1b  = (const float*)d_in[2];
  const float* ln2w  = (const float*)d_in[3];
  const float* ln2b  = (const float*)d_in[4];
  const float* qkvw  = (const float*)d_in[5];
  const float* qkvb  = (const float*)d_in[6];
  const float* projw = (const float*)d_in[7];
  const float* projb = (const float*)d_in[8];
  const float* lin1w = (const float*)d_in[9];
  const float* lin1b = (const float*)d_in[10];
  const float* lin2w = (const float*)d_in[11];
  const float* lin2b = (const float*)d_in[12];
  const float* rph   = (const float*)d_in[13];
  const float* rpw   = (const float*)d_in[14];
  const float* as    = (const float*)d_in[15];
  const float* wsc   = (const float*)d_in[16];
  float* out = (float*)d_out;

  // ws layout (72,462,336 B total), regions reused across stages:
  char* ws = (char*)d_ws;
  i8* big    = (i8*)ws;                          // 50,331,648
  i8* qq     = big;                              // 15,052,800 (1200*196*64)
  i8* kq     = big + 15052800;                   // 15,052,800
  i8* vt     = big + 30105600;                   // 19,660,800 (1200*64*256)
  short* TB  = (short*)(big + 49766400);         //     16,384 (rel tables; dead before lin1)
  i8* mlpq   = big;                              // 50,331,648 (16384*3072), after attn
  i8* creg   = (i8*)(ws + 50331648);             // 15,052,800
  i8* winq   = creg;                             // qkv input
  i8* attno  = creg;                             // proj input (after qkv dead)
  i8* yq     = creg;                             // lin1 input (after proj dead)
  i8* wqb    = (i8*)(ws + 65384448);             //  7,077,888
  i8* qkvwq  = wqb;
  i8* projwq = wqb + 1769472;
  i8* lin1wq = projwq + 589824;
  i8* lin2wq = lin1wq + 2359296;

  k_wquant<<<(110592 + 255) / 256, 256, 0, stream>>>(qkvw,  qkvwq,  110592, wsc, 0);
  k_wquant<<<( 36864 + 255) / 256, 256, 0, stream>>>(projw, projwq,  36864, wsc, 1);
  k_wquant<<<(147456 + 255) / 256, 256, 0, stream>>>(lin1w, lin1wq, 147456, wsc, 2);
  k_wquant<<<(147456 + 255) / 256, 256, 0, stream>>>(lin2w, lin2wq, 147456, wsc, 3);
  k_relpack<<<4, 256, 0, stream>>>(rph, rpw, TB);

  k_ln1<<<4900, 256, 0, stream>>>(x, ln1w, ln1b, as, winq);

  { EpiQKV e{as, wsc, qkvb, qq, kq, vt};
    k_gemm<EpiQKV><<<dim3(18, 154), 256, 0, stream>>>(winq, qkvwq, 19600, 2304, 768, e); }

  k_attn<<<dim3(13, 1200), 64, 0, stream>>>(qq, kq, vt, TB, as, attno);

  { EpiProj e{as, wsc, projb, x, out};
    k_gemm<EpiProj><<<dim3(6, 154), 256, 0, stream>>>(attno, projwq, 19600, 768, 768, e); }

  k_ln2<<<4096, 256, 0, stream>>>(out, ln2w, ln2b, as, yq);

  { EpiLin1 e{as, wsc, lin1b, mlpq};
    k_gemm<EpiLin1><<<dim3(24, 128), 256, 0, stream>>>(yq, lin1wq, 16384, 3072, 768, e); }

  { EpiLin2 e{as, wsc, lin2b, out};
    k_gemm<EpiLin2><<<dim3(6, 128), 256, 0, stream>>>(mlpq, lin2wq, 16384, 768, 3072, e); }
}

// Round 2
// 493.129 us; speedup vs baseline: 1.2172x; 1.0328x over previous
//
#include <hip/hip_runtime.h>
#include <cstdint>

// ============================================================================
// QunatEncoderBlock: windowed attention block with int8 fake-quant.
// All qlinear / QK^T / PV matmuls are EXACT in int8xint8->int32 (MFMA i8).
// Rel-pos bias via bf16 MFMA with hi/lo split tables (error ~2^-18).
// R1: k_attn 1-wave/1-tile blocks (grid 13x1200, 64 thr) -> 152->~?us.
// R2: k_gemm double-buffered LDS w/ prefetch-before-compute (T3-minimum
//     2-phase: stage(t+1) issued before ds_read/MFMA of t, ONE barrier per
//     K-step) + branch-free erf (A-S 7.1.26, |eps|<=1.5e-7) in EpiLin1.
//     lin1-GEMM was VALU-bound (VALUBusy 59%, MfmaUtil 17%): libm erff
//     epilogue ~2x main-loop cycles + exposed stage latency.
// ============================================================================

typedef int   v4i __attribute__((ext_vector_type(4)));
typedef float v4f __attribute__((ext_vector_type(4)));
typedef short v8s __attribute__((ext_vector_type(8)));
typedef int8_t i8;

__device__ __forceinline__ i8 satq(float x) {   // x already scale-divided
  float q = rintf(x);
  q = fminf(127.f, fmaxf(-128.f, q));
  return (i8)(int)q;
}

__device__ __forceinline__ void gload16(const i8* g, i8* l) {
  __builtin_amdgcn_global_load_lds((const __attribute__((address_space(1))) void*)g,
                                   (__attribute__((address_space(3))) void*)l, 16, 0, 0);
}

__device__ __forceinline__ int pack4(const i8* q) {
  return ((int)(unsigned char)q[0]) | ((int)(unsigned char)q[1] << 8) |
         ((int)(unsigned char)q[2] << 16) | ((int)(unsigned char)q[3] << 24);
}

// branch-free gelu: 0.5*v*(1+erf(v/sqrt2)), erf via A-S 7.1.26 (|err|<=1.5e-7)
__device__ __forceinline__ float fast_gelu(float v) {
  float x = fabsf(v) * 0.70710678118654752f;
  float t = __builtin_amdgcn_rcpf(fmaf(0.3275911f, x, 1.0f));
  float s = fmaf(1.061405429f, t, -1.453152027f);
  s = fmaf(s, t, 1.421413741f);
  s = fmaf(s, t, -0.284496736f);
  s = fmaf(s, t, 0.254829592f);
  s = s * t;
  float e = __expf(-x * x);
  float erfa = fmaf(-s, e, 1.0f);          // erf(|x|)
  float erfs = copysignf(erfa, v);
  float hv = 0.5f * v;
  return fmaf(hv, erfs, hv);
}

// ---------------------------------------------------------------------------
// weight fake-quant -> int8, 16 elements/thread
// ---------------------------------------------------------------------------
__global__ __launch_bounds__(256) void k_wquant(const float* __restrict__ w,
                                                i8* __restrict__ o, int n16,
                                                const float* __restrict__ wsc, int sidx) {
  int i = blockIdx.x * 256 + threadIdx.x;
  if (i >= n16) return;
  float inv = 1.0f / wsc[sidx];
  const float4* src = (const float4*)w + (size_t)i * 4;
  i8 buf[16];
#pragma unroll
  for (int t = 0; t < 4; t++) {
    float4 f = src[t];
    buf[t*4+0] = satq(f.x * inv); buf[t*4+1] = satq(f.y * inv);
    buf[t*4+2] = satq(f.z * inv); buf[t*4+3] = satq(f.w * inv);
  }
  *(v4i*)(o + (size_t)i * 16) = *(v4i*)buf;
}

// ---------------------------------------------------------------------------
// pack rel-pos tables for bf16 MFMA B-operand, hi/lo split.
// chunk c = (tb*2+nt)*4 + ks*2 + p ; frag = TB[c*512 + lane*8 .. +8]
// B[n][k] = table[n*64+k] (n<27 else 0), n = nt*16+(lane&15), k = ks*32+(lane>>4)*8+j
// ---------------------------------------------------------------------------
__global__ __launch_bounds__(256) void k_relpack(const float* __restrict__ rph,
    const float* __restrict__ rpw, short* __restrict__ TB) {
  int g = blockIdx.x * 256 + threadIdx.x;
  if (g >= 1024) return;
  int lane = g & 63, c = g >> 6;
  int p = c & 1, ks = (c >> 1) & 1, nt = (c >> 2) & 1, tb = c >> 3;
  const float* src = tb ? rpw : rph;
  int n = nt * 16 + (lane & 15);
  int k0 = ks * 32 + (lane >> 4) * 8;
  short outv[8];
#pragma unroll
  for (int j = 0; j < 8; j++) {
    float v = (n < 27) ? src[n * 64 + k0 + j] : 0.f;
    unsigned u = __float_as_uint(v);
    unsigned hi = (u + 0x7fffu + ((u >> 16) & 1u)) >> 16;
    if (p == 0) outv[j] = (short)hi;
    else {
      float lof = v - __uint_as_float(hi << 16);
      unsigned ul = __float_as_uint(lof);
      outv[j] = (short)((ul + 0x7fffu + ((ul >> 16) & 1u)) >> 16);
    }
  }
  *(v8s*)(TB + (size_t)c * 512 + lane * 8) = *(v8s*)outv;
}

// ---------------------------------------------------------------------------
// LN1: wave per window-token (pad 64->70, 5x5 windows of 14x14), quant a_s[4]
// ---------------------------------------------------------------------------
__global__ __launch_bounds__(256) void k_ln1(const float* __restrict__ x,
    const float* __restrict__ w, const float* __restrict__ b,
    const float* __restrict__ as, i8* __restrict__ outq) {
  int wt = blockIdx.x * 4 + (threadIdx.x >> 6);
  int lane = threadIdx.x & 63;
  int win = wt / 196, tok = wt - win * 196;
  int bb = win / 25, wrem = win - bb * 25, wh = wrem / 5, ww = wrem - wh * 5;
  int r = tok / 14, c = tok - r * 14;
  int y = wh * 14 + r, xx = ww * 14 + c;
  i8* dst = outq + (size_t)wt * 768 + lane * 12;
  if (y >= 64 || xx >= 64) {
    ((int*)dst)[0] = 0; ((int*)dst)[1] = 0; ((int*)dst)[2] = 0;
    return;
  }
  const float* row = x + (((size_t)bb * 64 + y) * 64 + xx) * 768 + lane * 12;
  float v[12];
  *(float4*)(v)     = *(const float4*)(row);
  *(float4*)(v + 4) = *(const float4*)(row + 4);
  *(float4*)(v + 8) = *(const float4*)(row + 8);
  float s = 0.f, ss = 0.f;
#pragma unroll
  for (int j = 0; j < 12; j++) { s += v[j]; ss += v[j] * v[j]; }
#pragma unroll
  for (int off = 1; off < 64; off <<= 1) { s += __shfl_xor(s, off); ss += __shfl_xor(ss, off); }
  float mu = s * (1.0f / 768.0f);
  float var = ss * (1.0f / 768.0f) - mu * mu;
  float rstd = 1.0f / sqrtf(var + 1e-6f);
  float inv = 1.0f / as[4];
  float wv[12], bv[12];
  *(float4*)(wv)     = *(const float4*)(w + lane * 12);
  *(float4*)(wv + 4) = *(const float4*)(w + lane * 12 + 4);
  *(float4*)(wv + 8) = *(const float4*)(w + lane * 12 + 8);
  *(float4*)(bv)     = *(const float4*)(b + lane * 12);
  *(float4*)(bv + 4) = *(const float4*)(b + lane * 12 + 4);
  *(float4*)(bv + 8) = *(const float4*)(b + lane * 12 + 8);
  i8 q[12];
#pragma unroll
  for (int j = 0; j < 12; j++) q[j] = satq(((v[j] - mu) * rstd * wv[j] + bv[j]) * inv);
  ((int*)dst)[0] = pack4(q); ((int*)dst)[1] = pack4(q + 4); ((int*)dst)[2] = pack4(q + 8);
}

// ---------------------------------------------------------------------------
// LN2: wave per token, quant a_s[6]
// ---------------------------------------------------------------------------
__global__ __launch_bounds__(256) void k_ln2(const float* __restrict__ x2,
    const float* __restrict__ w, const float* __restrict__ b,
    const float* __restrict__ as, i8* __restrict__ outq) {
  int tokg = blockIdx.x * 4 + (threadIdx.x >> 6);
  int lane = threadIdx.x & 63;
  const float* row = x2 + (size_t)tokg * 768 + lane * 12;
  float v[12];
  *(float4*)(v)     = *(const float4*)(row);
  *(float4*)(v + 4) = *(const float4*)(row + 4);
  *(float4*)(v + 8) = *(const float4*)(row + 8);
  float s = 0.f, ss = 0.f;
#pragma unroll
  for (int j = 0; j < 12; j++) { s += v[j]; ss += v[j] * v[j]; }
#pragma unroll
  for (int off = 1; off < 64; off <<= 1) { s += __shfl_xor(s, off); ss += __shfl_xor(ss, off); }
  float mu = s * (1.0f / 768.0f);
  float var = ss * (1.0f / 768.0f) - mu * mu;
  float rstd = 1.0f / sqrtf(var + 1e-6f);
  float inv = 1.0f / as[6];
  float wv[12], bv[12];
  *(float4*)(wv)     = *(const float4*)(w + lane * 12);
  *(float4*)(wv + 4) = *(const float4*)(w + lane * 12 + 4);
  *(float4*)(wv + 8) = *(const float4*)(w + lane * 12 + 8);
  *(float4*)(bv)     = *(const float4*)(b + lane * 12);
  *(float4*)(bv + 4) = *(const float4*)(b + lane * 12 + 4);
  *(float4*)(bv + 8) = *(const float4*)(b + lane * 12 + 8);
  i8* dst = outq + (size_t)tokg * 768 + lane * 12;
  i8 q[12];
#pragma unroll
  for (int j = 0; j < 12; j++) q[j] = satq(((v[j] - mu) * rstd * wv[j] + bv[j]) * inv);
  ((int*)dst)[0] = pack4(q); ((int*)dst)[1] = pack4(q + 4); ((int*)dst)[2] = pack4(q + 8);
}

// ---------------------------------------------------------------------------
// int8 GEMM: C[M,N] = A[M,K] x B[N,K]^T, 128x128 tile, BK=64.
// R2: double-buffered LDS, prefetch issued BEFORE compute, 1 barrier/K-step.
// global_load_lds width-16 staging. N%128==0, K%64==0, M%4==0.
// ---------------------------------------------------------------------------
template <class Epi>
__global__ __launch_bounds__(256) void k_gemm(const i8* __restrict__ A, const i8* __restrict__ B,
                                              int M, int N, int K, Epi epi) {
  __shared__ __align__(16) i8 As[2][128 * 64];
  __shared__ __align__(16) i8 Bs[2][128 * 64];
  const int tid = threadIdx.x;
  const int lane = tid & 63, wave = tid >> 6;
  const int quad = lane >> 4, lc = lane & 15;
  const int wr = wave >> 1, wc = wave & 1;
  const long bm = (long)blockIdx.y * 128, bn = (long)blockIdx.x * 128;
  const v4i vz = {0, 0, 0, 0};
  v4i acc[4][4];
#pragma unroll
  for (int i = 0; i < 4; i++)
#pragma unroll
    for (int j = 0; j < 4; j++) acc[i][j] = vz;

  const int r0 = tid >> 2, c0 = tid & 3;
  long rA0 = bm + r0;      if (rA0 >= M) rA0 = 0;
  long rA1 = bm + r0 + 64; if (rA1 >= M) rA1 = 0;
  const i8* pA0 = A + rA0 * (size_t)K + c0 * 16;
  const i8* pA1 = A + rA1 * (size_t)K + c0 * 16;
  const i8* pB0 = B + (bn + r0)      * (size_t)K + c0 * 16;
  const i8* pB1 = B + (bn + r0 + 64) * (size_t)K + c0 * 16;

  auto stage = [&](int buf) {
    gload16(pA0, As[buf] + tid * 16); gload16(pA1, As[buf] + 4096 + tid * 16);
    gload16(pB0, Bs[buf] + tid * 16); gload16(pB1, Bs[buf] + 4096 + tid * 16);
    pA0 += 64; pA1 += 64; pB0 += 64; pB1 += 64;
  };

  stage(0);
  __syncthreads();                      // vmcnt(0) drain + barrier: buf0 ready
  const int nt = K >> 6;
  int cur = 0;
  for (int t = 0; t < nt; ++t) {
    if (t + 1 < nt) stage(cur ^ 1);     // prefetch next tile: latency hides under MFMA
    v4i af[4], bf[4];
#pragma unroll
    for (int i = 0; i < 4; i++) af[i] = *(const v4i*)(As[cur] + (wr * 64 + i * 16 + lc) * 64 + quad * 16);
#pragma unroll
    for (int j = 0; j < 4; j++) bf[j] = *(const v4i*)(Bs[cur] + (wc * 64 + j * 16 + lc) * 64 + quad * 16);
#pragma unroll
    for (int i = 0; i < 4; i++)
#pragma unroll
      for (int j = 0; j < 4; j++)
        acc[i][j] = __builtin_amdgcn_mfma_i32_16x16x64_i8(af[i], bf[j], acc[i][j], 0, 0, 0);
    if (t + 1 < nt) __syncthreads();    // drain prefetch + barrier (uniform cond)
    cur ^= 1;
  }
  Epi e = epi;
  e.init();
#pragma unroll
  for (int i = 0; i < 4; i++) {
    int gm0 = (int)bm + wr * 64 + i * 16 + quad * 4;   // C/D: row=quad*4+reg, col=lc
#pragma unroll
    for (int j = 0; j < 4; j++) {
      int gn = (int)bn + wc * 64 + j * 16 + lc;
      if (gm0 < M) e.store4(acc[i][j], gm0, gn);
    }
  }
}

// -------- epilogues (store4: 4 consecutive rows m0..m0+3, all < M) --------
struct EpiQKV {   // split into q,k (token-major) and v^T (ch-major, stride 256)
  const float* as; const float* wsc; const float* bias;
  i8 *qq, *kq, *vt;
  float sab, invq, invk, invv;
  __device__ void init() {
    sab = as[4] * wsc[0]; invq = 1.f / as[0]; invk = 1.f / as[1]; invv = 1.f / as[2];
  }
  __device__ void store4(const v4i a, int m0, int n) {
    int t = n / 768, rem = n - t * 768;
    int head = rem >> 6, ch = rem & 63;
    int win = m0 / 196, tok0 = m0 - win * 196;   // m0%4==0, 196%4==0: no window straddle
    size_t bh = (size_t)win * 12 + head;
    float bv = bias[n];
    if (t == 2) {
      i8 q[4];
#pragma unroll
      for (int r = 0; r < 4; r++) q[r] = satq(((float)a[r] * sab + bv) * invv);
      *(int*)(vt + (bh * 64 + ch) * 256 + tok0) = pack4(q);
    } else {
      float inv = (t == 0) ? invq : invk;
      i8* dst = (t == 0 ? qq : kq) + (bh * 196 + tok0) * 64 + ch;
#pragma unroll
      for (int r = 0; r < 4; r++) dst[(size_t)r * 64] = satq(((float)a[r] * sab + bv) * inv);
    }
  }
};

struct EpiProj {  // window reverse + unpad + shortcut add -> x2 (in d_out)
  const float* as; const float* wsc; const float* bias; const float* x0; float* out;
  float sab;
  __device__ void init() { sab = as[5] * wsc[1]; }
  __device__ void store4(const v4i a, int m0, int n) {
    int win = m0 / 196, tok0 = m0 - win * 196;
    int bb = win / 25, wrem = win - bb * 25, wh = wrem / 5, ww = wrem - wh * 5;
    float bv = bias[n];
#pragma unroll
    for (int r = 0; r < 4; r++) {
      int tok = tok0 + r;
      int rr = tok / 14, cc = tok - rr * 14;
      int y = wh * 14 + rr, xx = ww * 14 + cc;
      if (y < 64 && xx < 64) {
        size_t o = (((size_t)bb * 64 + y) * 64 + xx) * 768 + n;
        out[o] = (float)a[r] * sab + bv + x0[o];
      }
    }
  }
};

struct EpiLin1 {  // bias + branch-free gelu + quant a_s[7]
  const float* as; const float* wsc; const float* bias; i8* outq;
  float sab, invg;
  __device__ void init() { sab = as[6] * wsc[2]; invg = 1.f / as[7]; }
  __device__ void store4(const v4i a, int m0, int n) {
    float bv = bias[n];
#pragma unroll
    for (int r = 0; r < 4; r++) {
      float v = fmaf((float)a[r], sab, bv);
      outq[(size_t)(m0 + r) * 3072 + n] = satq(fast_gelu(v) * invg);
    }
  }
};

struct EpiLin2 {  // bias + residual add into d_out
  const float* as; const float* wsc; const float* bias; float* out;
  float sab;
  __device__ void init() { sab = as[7] * wsc[3]; }
  __device__ void store4(const v4i a, int m0, int n) {
    float bv = bias[n];
#pragma unroll
    for (int r = 0; r < 4; r++) {
      size_t o = (size_t)(m0 + r) * 768 + n;
      out[o] += (float)a[r] * sab + bv;
    }
  }
};

// ---------------------------------------------------------------------------
// attention: ONE WAVE per (win*12+head, 16-row tile). Grid (13, 1200), 64 thr.
// No inter-wave communication; 8.6KB LDS + <=128 VGPR -> 16 waves/CU.
// Rel-pos bias via bf16 MFMA (hi/lo split tables). QK^T & PV via i8 MFMA.
// ---------------------------------------------------------------------------
__global__ __launch_bounds__(64, 4) void k_attn(const i8* __restrict__ qq, const i8* __restrict__ kq,
    const i8* __restrict__ vt, const short* __restrict__ TB,
    const float* __restrict__ as, i8* __restrict__ outq) {
  __shared__ __align__(16) i8 Ps[16 * 272];       // this wave's P tile
  __shared__ float relS[16][66];                  // rel bias [row][d(h)|32+d(w)], stride 66: 2-way banks
  const int t = blockIdx.x, bh = blockIdx.y;
  const int win = bh / 12, head = bh - win * 12;
  const int lane = threadIdx.x;
  const int quad = lane >> 4, lc = lane & 15;
  const float s0 = as[0];
  const float ssc = s0 * as[1] * 0.125f;
  const float invs3 = 1.0f / as[3];
  const float oscale = as[2] * as[3] / as[5];

  // zero pad cols [192,256)
  for (int idx = lane; idx < 256; idx += 64)
    *(int*)(Ps + (idx >> 4) * 272 + 192 + (idx & 15) * 4) = 0;

  // per-lane col decomposition, byte-packed (kh,kw <= 13): saves ~18 VGPR
  unsigned ckhp[4] = {0, 0, 0, 0}, ckwp[4] = {0, 0, 0, 0};
#pragma unroll
  for (int f = 0; f < 13; f++) {
    int col = f * 16 + lc; if (col > 195) col = 195;
    int kh = col / 14, kw = col - kh * 14;
    ckhp[f >> 2] |= (unsigned)kh << ((f & 3) * 8);
    ckwp[f >> 2] |= (unsigned)kw << ((f & 3) * 8);
  }

  const v8s* TBv = (const v8s*)TB;
  const v4i vz = {0, 0, 0, 0};

  // ---- rel-pos bias via bf16 MFMA ----
  {
    int arow = t * 16 + lc; if (arow > 195) arow = 195;
    const i8* qrow = qq + ((size_t)bh * 196 + arow) * 64;
    v8s af[2];
#pragma unroll
    for (int ks = 0; ks < 2; ks++) {
      const i8* p = qrow + ks * 32 + quad * 8;
#pragma unroll
      for (int j = 0; j < 8; j++)
        af[ks][j] = (short)(__float_as_uint((float)p[j]) >> 16);  // exact int->bf16
    }
    v4f rh0 = {0,0,0,0}, rh1 = {0,0,0,0}, rw0 = {0,0,0,0}, rw1 = {0,0,0,0};
#pragma unroll
    for (int ks = 0; ks < 2; ks++)
#pragma unroll
      for (int p2 = 0; p2 < 2; p2++) {
        rh0 = __builtin_amdgcn_mfma_f32_16x16x32_bf16(af[ks], TBv[(0*4 + ks*2 + p2)*64 + lane], rh0, 0, 0, 0);
        rh1 = __builtin_amdgcn_mfma_f32_16x16x32_bf16(af[ks], TBv[(1*4 + ks*2 + p2)*64 + lane], rh1, 0, 0, 0);
        rw0 = __builtin_amdgcn_mfma_f32_16x16x32_bf16(af[ks], TBv[(2*4 + ks*2 + p2)*64 + lane], rw0, 0, 0, 0);
        rw1 = __builtin_amdgcn_mfma_f32_16x16x32_bf16(af[ks], TBv[(3*4 + ks*2 + p2)*64 + lane], rw1, 0, 0, 0);
      }
#pragma unroll
    for (int r = 0; r < 4; r++) {
      int rl = quad * 4 + r;
      relS[rl][lc]      = rh0[r] * s0;
      relS[rl][16 + lc] = rh1[r] * s0;
      relS[rl][32 + lc] = rw0[r] * s0;
      relS[rl][48 + lc] = rw1[r] * s0;
    }
  }

  // ---- QK^T (int-exact) ----
  v4i aq = *(const v4i*)(qq + ((size_t)bh * 196 + t * 16 + lc) * 64 + quad * 16);
  v4i sacc[13];
#pragma unroll
  for (int f = 0; f < 13; f++) {
    v4i bk = *(const v4i*)(kq + ((size_t)bh * 196 + f * 16 + lc) * 64 + quad * 16);
    sacc[f] = __builtin_amdgcn_mfma_i32_16x16x64_i8(aq, bk, vz, 0, 0, 0);
  }

  // ---- softmax + P quant ----
#pragma unroll
  for (int r = 0; r < 4; r++) {
    int rl = quad * 4 + r;
    int row = t * 16 + rl;
    int qh = row / 14, qw = row - qh * 14;
    const float* rH = &relS[rl][13 + qh];        // rH[-kh]
    const float* rW = &relS[rl][32 + 13 + qw];   // rW[-kw]
    float L[13];
#pragma unroll
    for (int f = 0; f < 13; f++) {
      int kh = (int)((ckhp[f >> 2] >> ((f & 3) * 8)) & 0xffu);
      int kw = (int)((ckwp[f >> 2] >> ((f & 3) * 8)) & 0xffu);
      // cok = col<196  <=>  f<12 || lc<4  (compile-time for f<12 under unroll)
      L[f] = ((f < 12) | (lc < 4)) ? fmaf((float)sacc[f][r], ssc, rH[-kh] + rW[-kw]) : -1e30f;
    }
    float mx = L[0];
#pragma unroll
    for (int f = 1; f < 13; f++) mx = fmaxf(mx, L[f]);
#pragma unroll
    for (int off = 1; off < 16; off <<= 1) mx = fmaxf(mx, __shfl_xor(mx, off));
    float sum = 0.f;
#pragma unroll
    for (int f = 0; f < 13; f++) { float e = __expf(L[f] - mx); L[f] = e; sum += e; }
#pragma unroll
    for (int off = 1; off < 16; off <<= 1) sum += __shfl_xor(sum, off);
    float cq = (1.0f / sum) * invs3;
#pragma unroll
    for (int f = 0; f < 13; f++)
      Ps[rl * 272 + f * 16 + lc] = satq(L[f] * cq);
  }

  // ---- PV (int-exact) ----
  v4i oacc[4];
#pragma unroll
  for (int nt = 0; nt < 4; nt++) oacc[nt] = vz;
#pragma unroll
  for (int kc = 0; kc < 4; kc++) {
    v4i ap = *(const v4i*)(Ps + lc * 272 + kc * 64 + quad * 16);
#pragma unroll
    for (int nt = 0; nt < 4; nt++) {
      v4i bv = *(const v4i*)(vt + ((size_t)bh * 64 + nt * 16 + lc) * 256 + kc * 64 + quad * 16);
      oacc[nt] = __builtin_amdgcn_mfma_i32_16x16x64_i8(ap, bv, oacc[nt], 0, 0, 0);
    }
  }
#pragma unroll
  for (int nt = 0; nt < 4; nt++) {
    int ch = nt * 16 + lc;
#pragma unroll
    for (int r = 0; r < 4; r++) {
      int row = t * 16 + quad * 4 + r;
      if (row < 196)
        outq[((size_t)win * 196 + row) * 768 + head * 64 + ch] = satq((float)oacc[nt][r] * oscale);
    }
  }
}

// ---------------------------------------------------------------------------
extern "C" void kernel_launch(void* const* d_in, const int* in_sizes, int n_in,
                              void* d_out, int out_size, void* d_ws, size_t ws_size,
                              hipStream_t stream) {
  const float* x     = (const float*)d_in[0];
  const float* ln1w  = (const float*)d_in[1];
  const float* ln1b  = (const float*)d_in[2];
  const float* ln2w  = (const float*)d_in[3];
  const float* ln2b  = (const float*)d_in[4];
  const float* qkvw  = (const float*)d_in[5];
  const float* qkvb  = (const float*)d_in[6];
  const float* projw = (const float*)d_in[7];
  const float* projb = (const float*)d_in[8];
  const float* lin1w = (const float*)d_in[9];
  const float* lin1b = (const float*)d_in[10];
  const float* lin2w = (const float*)d_in[11];
  const float* lin2b = (const float*)d_in[12];
  const float* rph   = (const float*)d_in[13];
  const float* rpw   = (const float*)d_in[14];
  const float* as    = (const float*)d_in[15];
  const float* wsc   = (const float*)d_in[16];
  float* out = (float*)d_out;

  // ws layout (72,462,336 B total), regions reused across stages:
  char* ws = (char*)d_ws;
  i8* big    = (i8*)ws;                          // 50,331,648
  i8* qq     = big;                              // 15,052,800 (1200*196*64)
  i8* kq     = big + 15052800;                   // 15,052,800
  i8* vt     = big + 30105600;                   // 19,660,800 (1200*64*256)
  short* TB  = (short*)(big + 49766400);         //     16,384 (rel tables; dead before lin1)
  i8* mlpq   = big;                              // 50,331,648 (16384*3072), after attn
  i8* creg   = (i8*)(ws + 50331648);             // 15,052,800
  i8* winq   = creg;                             // qkv input
  i8* attno  = creg;                             // proj input (after qkv dead)
  i8* yq     = creg;                             // lin1 input (after proj dead)
  i8* wqb    = (i8*)(ws + 65384448);             //  7,077,888
  i8* qkvwq  = wqb;
  i8* projwq = wqb + 1769472;
  i8* lin1wq = projwq + 589824;
  i8* lin2wq = lin1wq + 2359296;

  k_wquant<<<(110592 + 255) / 256, 256, 0, stream>>>(qkvw,  qkvwq,  110592, wsc, 0);
  k_wquant<<<( 36864 + 255) / 256, 256, 0, stream>>>(projw, projwq,  36864, wsc, 1);
  k_wquant<<<(147456 + 255) / 256, 256, 0, stream>>>(lin1w, lin1wq, 147456, wsc, 2);
  k_wquant<<<(147456 + 255) / 256, 256, 0, stream>>>(lin2w, lin2wq, 147456, wsc, 3);
  k_relpack<<<4, 256, 0, stream>>>(rph, rpw, TB);

  k_ln1<<<4900, 256, 0, stream>>>(x, ln1w, ln1b, as, winq);

  { EpiQKV e{as, wsc, qkvb, qq, kq, vt};
    k_gemm<EpiQKV><<<dim3(18, 154), 256, 0, stream>>>(winq, qkvwq, 19600, 2304, 768, e); }

  k_attn<<<dim3(13, 1200), 64, 0, stream>>>(qq, kq, vt, TB, as, attno);

  { EpiProj e{as, wsc, projb, x, out};
    k_gemm<EpiProj><<<dim3(6, 154), 256, 0, stream>>>(attno, projwq, 19600, 768, 768, e); }

  k_ln2<<<4096, 256, 0, stream>>>(out, ln2w, ln2b, as, yq);

  { EpiLin1 e{as, wsc, lin1b, mlpq};
    k_gemm<EpiLin1><<<dim3(24, 128), 256, 0, stream>>>(yq, lin1wq, 16384, 3072, 768, e); }

  { EpiLin2 e{as, wsc, lin2b, out};
    k_gemm<EpiLin2><<<dim3(6, 128), 256, 0, stream>>>(mlpq, lin2wq, 16384, 768, 3072, e); }
}

// Round 3
// 477.755 us; speedup vs baseline: 1.2563x; 1.0322x over previous
//
#include <hip/hip_runtime.h>
#include <cstdint>

// ============================================================================
// QunatEncoderBlock: windowed attention block with int8 fake-quant.
// All qlinear / QK^T / PV matmuls are EXACT in int8xint8->int32 (MFMA i8).
// Rel-pos bias via bf16 MFMA with hi/lo split tables (error ~2^-18).
// R1: k_attn 1-wave/1-tile blocks (grid 13x1200, 64 thr): 152->~60us.
// R2: gemm 2-phase dbuf + branch-free erf gelu: lin1 99->89us.
// R3: k_gemm depth-2 pipeline (3 LDS bufs, counted s_waitcnt vmcnt(4) +
//     raw s_barrier: loads span 2 K-steps, never drain to 0 mid-loop);
//     chunk-XOR LDS swizzle (source-side pre-swizzle, rule #21: linear
//     gload_lds dest + XOR'd global src + XOR'd ds_read) kills the 8-way
//     read conflict (4.7M conflict cycles/dispatch); operand-swapped MFMA
//     (mfma(bf,af)) so lanes hold 4 consecutive N -> packed dword / float4
//     epilogue stores (4x fewer VMEM instr in every epilogue).
// ============================================================================

typedef int   v4i __attribute__((ext_vector_type(4)));
typedef float v4f __attribute__((ext_vector_type(4)));
typedef short v8s __attribute__((ext_vector_type(8)));
typedef int8_t i8;

__device__ __forceinline__ i8 satq(float x) {   // x already scale-divided
  float q = rintf(x);
  q = fminf(127.f, fmaxf(-128.f, q));
  return (i8)(int)q;
}

__device__ __forceinline__ void gload16(const i8* g, i8* l) {
  __builtin_amdgcn_global_load_lds((const __attribute__((address_space(1))) void*)g,
                                   (__attribute__((address_space(3))) void*)l, 16, 0, 0);
}

__device__ __forceinline__ int pack4(const i8* q) {
  return ((int)(unsigned char)q[0]) | ((int)(unsigned char)q[1] << 8) |
         ((int)(unsigned char)q[2] << 16) | ((int)(unsigned char)q[3] << 24);
}

// branch-free gelu: 0.5*v*(1+erf(v/sqrt2)), erf via A-S 7.1.26 (|err|<=1.5e-7)
__device__ __forceinline__ float fast_gelu(float v) {
  float x = fabsf(v) * 0.70710678118654752f;
  float t = __builtin_amdgcn_rcpf(fmaf(0.3275911f, x, 1.0f));
  float s = fmaf(1.061405429f, t, -1.453152027f);
  s = fmaf(s, t, 1.421413741f);
  s = fmaf(s, t, -0.284496736f);
  s = fmaf(s, t, 0.254829592f);
  s = s * t;
  float e = __expf(-x * x);
  float erfa = fmaf(-s, e, 1.0f);          // erf(|x|)
  float erfs = copysignf(erfa, v);
  float hv = 0.5f * v;
  return fmaf(hv, erfs, hv);
}

// ---------------------------------------------------------------------------
// weight fake-quant -> int8, 16 elements/thread
// ---------------------------------------------------------------------------
__global__ __launch_bounds__(256) void k_wquant(const float* __restrict__ w,
                                                i8* __restrict__ o, int n16,
                                                const float* __restrict__ wsc, int sidx) {
  int i = blockIdx.x * 256 + threadIdx.x;
  if (i >= n16) return;
  float inv = 1.0f / wsc[sidx];
  const float4* src = (const float4*)w + (size_t)i * 4;
  i8 buf[16];
#pragma unroll
  for (int t = 0; t < 4; t++) {
    float4 f = src[t];
    buf[t*4+0] = satq(f.x * inv); buf[t*4+1] = satq(f.y * inv);
    buf[t*4+2] = satq(f.z * inv); buf[t*4+3] = satq(f.w * inv);
  }
  *(v4i*)(o + (size_t)i * 16) = *(v4i*)buf;
}

// ---------------------------------------------------------------------------
// pack rel-pos tables for bf16 MFMA B-operand, hi/lo split.
// chunk c = (tb*2+nt)*4 + ks*2 + p ; frag = TB[c*512 + lane*8 .. +8]
// B[n][k] = table[n*64+k] (n<27 else 0), n = nt*16+(lane&15), k = ks*32+(lane>>4)*8+j
// ---------------------------------------------------------------------------
__global__ __launch_bounds__(256) void k_relpack(const float* __restrict__ rph,
    const float* __restrict__ rpw, short* __restrict__ TB) {
  int g = blockIdx.x * 256 + threadIdx.x;
  if (g >= 1024) return;
  int lane = g & 63, c = g >> 6;
  int p = c & 1, ks = (c >> 1) & 1, nt = (c >> 2) & 1, tb = c >> 3;
  const float* src = tb ? rpw : rph;
  int n = nt * 16 + (lane & 15);
  int k0 = ks * 32 + (lane >> 4) * 8;
  short outv[8];
#pragma unroll
  for (int j = 0; j < 8; j++) {
    float v = (n < 27) ? src[n * 64 + k0 + j] : 0.f;
    unsigned u = __float_as_uint(v);
    unsigned hi = (u + 0x7fffu + ((u >> 16) & 1u)) >> 16;
    if (p == 0) outv[j] = (short)hi;
    else {
      float lof = v - __uint_as_float(hi << 16);
      unsigned ul = __float_as_uint(lof);
      outv[j] = (short)((ul + 0x7fffu + ((ul >> 16) & 1u)) >> 16);
    }
  }
  *(v8s*)(TB + (size_t)c * 512 + lane * 8) = *(v8s*)outv;
}

// ---------------------------------------------------------------------------
// LN1: wave per window-token (pad 64->70, 5x5 windows of 14x14), quant a_s[4]
// ---------------------------------------------------------------------------
__global__ __launch_bounds__(256) void k_ln1(const float* __restrict__ x,
    const float* __restrict__ w, const float* __restrict__ b,
    const float* __restrict__ as, i8* __restrict__ outq) {
  int wt = blockIdx.x * 4 + (threadIdx.x >> 6);
  int lane = threadIdx.x & 63;
  int win = wt / 196, tok = wt - win * 196;
  int bb = win / 25, wrem = win - bb * 25, wh = wrem / 5, ww = wrem - wh * 5;
  int r = tok / 14, c = tok - r * 14;
  int y = wh * 14 + r, xx = ww * 14 + c;
  i8* dst = outq + (size_t)wt * 768 + lane * 12;
  if (y >= 64 || xx >= 64) {
    ((int*)dst)[0] = 0; ((int*)dst)[1] = 0; ((int*)dst)[2] = 0;
    return;
  }
  const float* row = x + (((size_t)bb * 64 + y) * 64 + xx) * 768 + lane * 12;
  float v[12];
  *(float4*)(v)     = *(const float4*)(row);
  *(float4*)(v + 4) = *(const float4*)(row + 4);
  *(float4*)(v + 8) = *(const float4*)(row + 8);
  float s = 0.f, ss = 0.f;
#pragma unroll
  for (int j = 0; j < 12; j++) { s += v[j]; ss += v[j] * v[j]; }
#pragma unroll
  for (int off = 1; off < 64; off <<= 1) { s += __shfl_xor(s, off); ss += __shfl_xor(ss, off); }
  float mu = s * (1.0f / 768.0f);
  float var = ss * (1.0f / 768.0f) - mu * mu;
  float rstd = 1.0f / sqrtf(var + 1e-6f);
  float inv = 1.0f / as[4];
  float wv[12], bv[12];
  *(float4*)(wv)     = *(const float4*)(w + lane * 12);
  *(float4*)(wv + 4) = *(const float4*)(w + lane * 12 + 4);
  *(float4*)(wv + 8) = *(const float4*)(w + lane * 12 + 8);
  *(float4*)(bv)     = *(const float4*)(b + lane * 12);
  *(float4*)(bv + 4) = *(const float4*)(b + lane * 12 + 4);
  *(float4*)(bv + 8) = *(const float4*)(b + lane * 12 + 8);
  i8 q[12];
#pragma unroll
  for (int j = 0; j < 12; j++) q[j] = satq(((v[j] - mu) * rstd * wv[j] + bv[j]) * inv);
  ((int*)dst)[0] = pack4(q); ((int*)dst)[1] = pack4(q + 4); ((int*)dst)[2] = pack4(q + 8);
}

// ---------------------------------------------------------------------------
// LN2: wave per token, quant a_s[6]
// ---------------------------------------------------------------------------
__global__ __launch_bounds__(256) void k_ln2(const float* __restrict__ x2,
    const float* __restrict__ w, const float* __restrict__ b,
    const float* __restrict__ as, i8* __restrict__ outq) {
  int tokg = blockIdx.x * 4 + (threadIdx.x >> 6);
  int lane = threadIdx.x & 63;
  const float* row = x2 + (size_t)tokg * 768 + lane * 12;
  float v[12];
  *(float4*)(v)     = *(const float4*)(row);
  *(float4*)(v + 4) = *(const float4*)(row + 4);
  *(float4*)(v + 8) = *(const float4*)(row + 8);
  float s = 0.f, ss = 0.f;
#pragma unroll
  for (int j = 0; j < 12; j++) { s += v[j]; ss += v[j] * v[j]; }
#pragma unroll
  for (int off = 1; off < 64; off <<= 1) { s += __shfl_xor(s, off); ss += __shfl_xor(ss, off); }
  float mu = s * (1.0f / 768.0f);
  float var = ss * (1.0f / 768.0f) - mu * mu;
  float rstd = 1.0f / sqrtf(var + 1e-6f);
  float inv = 1.0f / as[6];
  float wv[12], bv[12];
  *(float4*)(wv)     = *(const float4*)(w + lane * 12);
  *(float4*)(wv + 4) = *(const float4*)(w + lane * 12 + 4);
  *(float4*)(wv + 8) = *(const float4*)(w + lane * 12 + 8);
  *(float4*)(bv)     = *(const float4*)(b + lane * 12);
  *(float4*)(bv + 4) = *(const float4*)(b + lane * 12 + 4);
  *(float4*)(bv + 8) = *(const float4*)(b + lane * 12 + 8);
  i8* dst = outq + (size_t)tokg * 768 + lane * 12;
  i8 q[12];
#pragma unroll
  for (int j = 0; j < 12; j++) q[j] = satq(((v[j] - mu) * rstd * wv[j] + bv[j]) * inv);
  ((int*)dst)[0] = pack4(q); ((int*)dst)[1] = pack4(q + 4); ((int*)dst)[2] = pack4(q + 8);
}

// ---------------------------------------------------------------------------
// int8 GEMM: C[M,N] = A[M,K] x B[N,K]^T, 128x128 tile, BK=64.
// R3: depth-2 pipeline, 3 LDS buffers, counted vmcnt, raw barriers,
// chunk-XOR swizzle, operand-swapped MFMA. N%128==0, K%64==0, K>=128.
// Epi::store4(a, m, n0): a[r] = C[m][n0+r], n0%4==0, m<M guaranteed.
// ---------------------------------------------------------------------------
template <class Epi>
__global__ __launch_bounds__(256) void k_gemm(const i8* __restrict__ A, const i8* __restrict__ B,
                                              int M, int N, int K, Epi epi) {
  __shared__ __align__(16) i8 As[3][8192];
  __shared__ __align__(16) i8 Bs[3][8192];
  const int tid = threadIdx.x;
  const int lane = tid & 63, wave = tid >> 6;
  const int quad = lane >> 4, lc = lane & 15;
  const int wr = wave >> 1, wc = wave & 1;
  const long bm = (long)blockIdx.y * 128, bn = (long)blockIdx.x * 128;
  const v4i vz = {0, 0, 0, 0};
  v4i acc[4][4];
#pragma unroll
  for (int i = 0; i < 4; i++)
#pragma unroll
    for (int j = 0; j < 4; j++) acc[i][j] = vz;

  // staging: thread stages LDS rows r0, r0+64, chunk c0. Source chunk is
  // XOR-swizzled so linear LDS write yields LDS[r][c] = glob[r][c^f(r)],
  // f(r) = (r>>1)&3  (f(r0+64)==f(r0)).
  const int r0 = tid >> 2, c0 = tid & 3;
  const int cs = c0 ^ ((r0 >> 1) & 3);
  long rA0 = bm + r0;      if (rA0 >= M) rA0 = 0;
  long rA1 = bm + r0 + 64; if (rA1 >= M) rA1 = 0;
  const i8* pA0 = A + rA0 * (size_t)K + cs * 16;
  const i8* pA1 = A + rA1 * (size_t)K + cs * 16;
  const i8* pB0 = B + (bn + r0)      * (size_t)K + cs * 16;
  const i8* pB1 = B + (bn + r0 + 64) * (size_t)K + cs * 16;

  auto stage = [&](int buf) {
    gload16(pA0, As[buf] + tid * 16); gload16(pA1, As[buf] + 4096 + tid * 16);
    gload16(pB0, Bs[buf] + tid * 16); gload16(pB1, Bs[buf] + 4096 + tid * 16);
    pA0 += 64; pA1 += 64; pB0 += 64; pB1 += 64;
  };

  // read-side swizzle: rows wr*64+i*16+lc (base%16==0) -> f(row)=(lc>>1)&3
  const int xq16 = (quad ^ ((lc >> 1) & 3)) * 16;

  auto compute = [&](int buf) {
    v4i af[4], bf[4];
#pragma unroll
    for (int i = 0; i < 4; i++) af[i] = *(const v4i*)(As[buf] + (wr * 64 + i * 16 + lc) * 64 + xq16);
#pragma unroll
    for (int j = 0; j < 4; j++) bf[j] = *(const v4i*)(Bs[buf] + (wc * 64 + j * 16 + lc) * 64 + xq16);
#pragma unroll
    for (int i = 0; i < 4; i++)
#pragma unroll
      for (int j = 0; j < 4; j++)   // swapped operands: acc row ~ N, col ~ M
        acc[i][j] = __builtin_amdgcn_mfma_i32_16x16x64_i8(bf[j], af[i], acc[i][j], 0, 0, 0);
  };

  const int nt = K >> 6;
  stage(0); stage(1);               // tiles 0,1 in flight (8 loads/wave)
  int cb = 0, sb = 2;
  for (int t = 0; t < nt - 1; ++t) {
    // own 4 oldest (tile t) retired; tile t+1's 4 stay in flight
    asm volatile("s_waitcnt vmcnt(4)" ::: "memory");
    __builtin_amdgcn_s_barrier();
    asm volatile("" ::: "memory");
    if (t + 2 < nt) { stage(sb); if (++sb == 3) sb = 0; }
    compute(cb); if (++cb == 3) cb = 0;
  }
  asm volatile("s_waitcnt vmcnt(0)" ::: "memory");
  __builtin_amdgcn_s_barrier();
  asm volatile("" ::: "memory");
  compute(cb);

  Epi e = epi;
  e.init();
#pragma unroll
  for (int i = 0; i < 4; i++) {
    int gm = (int)bm + wr * 64 + i * 16 + lc;          // col of D' = M row
#pragma unroll
    for (int j = 0; j < 4; j++) {
      int gn0 = (int)bn + wc * 64 + j * 16 + quad * 4; // row of D' = N col
      if (gm < M) e.store4(acc[i][j], gm, gn0);
    }
  }
}

// -------- epilogues: store4(a, m, n0) with a[r] = C[m][n0+r], n0%4==0 ----
struct EpiQKV {   // split into q,k (token-major) and v^T (ch-major, stride 256)
  const float* as; const float* wsc; const float* bias;
  i8 *qq, *kq, *vt;
  float sab, invq, invk, invv;
  __device__ void init() {
    sab = as[4] * wsc[0]; invq = 1.f / as[0]; invk = 1.f / as[1]; invv = 1.f / as[2];
  }
  __device__ void store4(const v4i a, int m, int n0) {
    int t = n0 / 768, rem = n0 - t * 768;
    int head = rem >> 6, ch0 = rem & 63;              // ch0%4==0: same head for all 4
    int win = m / 196, tok = m - win * 196;
    size_t bh = (size_t)win * 12 + head;
    float4 bv = *(const float4*)(bias + n0);
    const float* bp = (const float*)&bv;
    if (t == 2) {
#pragma unroll
      for (int r = 0; r < 4; r++)
        vt[(bh * 64 + ch0 + r) * 256 + tok] = satq(((float)a[r] * sab + bp[r]) * invv);
    } else {
      float inv = (t == 0) ? invq : invk;
      i8 q[4];
#pragma unroll
      for (int r = 0; r < 4; r++) q[r] = satq(((float)a[r] * sab + bp[r]) * inv);
      *(int*)((t == 0 ? qq : kq) + (bh * 196 + tok) * 64 + ch0) = pack4(q);
    }
  }
};

struct EpiProj {  // window reverse + unpad + shortcut add -> x2 (in d_out)
  const float* as; const float* wsc; const float* bias; const float* x0; float* out;
  float sab;
  __device__ void init() { sab = as[5] * wsc[1]; }
  __device__ void store4(const v4i a, int m, int n0) {
    int win = m / 196, tok = m - win * 196;
    int bb = win / 25, wrem = win - bb * 25, wh = wrem / 5, ww = wrem - wh * 5;
    int rr = tok / 14, cc = tok - rr * 14;
    int y = wh * 14 + rr, xx = ww * 14 + cc;
    if (y >= 64 || xx >= 64) return;
    size_t o = (((size_t)bb * 64 + y) * 64 + xx) * 768 + n0;
    float4 bv = *(const float4*)(bias + n0);
    float4 xv = *(const float4*)(x0 + o);
    float4 ov;
    ov.x = (float)a[0] * sab + bv.x + xv.x;
    ov.y = (float)a[1] * sab + bv.y + xv.y;
    ov.z = (float)a[2] * sab + bv.z + xv.z;
    ov.w = (float)a[3] * sab + bv.w + xv.w;
    *(float4*)(out + o) = ov;
  }
};

struct EpiLin1 {  // bias + branch-free gelu + quant a_s[7]
  const float* as; const float* wsc; const float* bias; i8* outq;
  float sab, invg;
  __device__ void init() { sab = as[6] * wsc[2]; invg = 1.f / as[7]; }
  __device__ void store4(const v4i a, int m, int n0) {
    float4 bv = *(const float4*)(bias + n0);
    const float* bp = (const float*)&bv;
    i8 q[4];
#pragma unroll
    for (int r = 0; r < 4; r++) {
      float v = fmaf((float)a[r], sab, bp[r]);
      q[r] = satq(fast_gelu(v) * invg);
    }
    *(int*)(outq + (size_t)m * 3072 + n0) = pack4(q);
  }
};

struct EpiLin2 {  // bias + residual add into d_out
  const float* as; const float* wsc; const float* bias; float* out;
  float sab;
  __device__ void init() { sab = as[7] * wsc[3]; }
  __device__ void store4(const v4i a, int m, int n0) {
    size_t o = (size_t)m * 768 + n0;
    float4 bv = *(const float4*)(bias + n0);
    float4 ov = *(const float4*)(out + o);
    ov.x += (float)a[0] * sab + bv.x;
    ov.y += (float)a[1] * sab + bv.y;
    ov.z += (float)a[2] * sab + bv.z;
    ov.w += (float)a[3] * sab + bv.w;
    *(float4*)(out + o) = ov;
  }
};

// ---------------------------------------------------------------------------
// attention: ONE WAVE per (win*12+head, 16-row tile). Grid (13, 1200), 64 thr.
// No inter-wave communication; 8.6KB LDS + <=128 VGPR -> 16 waves/CU.
// Rel-pos bias via bf16 MFMA (hi/lo split tables). QK^T & PV via i8 MFMA.
// ---------------------------------------------------------------------------
__global__ __launch_bounds__(64, 4) void k_attn(const i8* __restrict__ qq, const i8* __restrict__ kq,
    const i8* __restrict__ vt, const short* __restrict__ TB,
    const float* __restrict__ as, i8* __restrict__ outq) {
  __shared__ __align__(16) i8 Ps[16 * 272];       // this wave's P tile
  __shared__ float relS[16][66];                  // rel bias [row][d(h)|32+d(w)], stride 66: 2-way banks
  const int t = blockIdx.x, bh = blockIdx.y;
  const int win = bh / 12, head = bh - win * 12;
  const int lane = threadIdx.x;
  const int quad = lane >> 4, lc = lane & 15;
  const float s0 = as[0];
  const float ssc = s0 * as[1] * 0.125f;
  const float invs3 = 1.0f / as[3];
  const float oscale = as[2] * as[3] / as[5];

  // zero pad cols [192,256)
  for (int idx = lane; idx < 256; idx += 64)
    *(int*)(Ps + (idx >> 4) * 272 + 192 + (idx & 15) * 4) = 0;

  // per-lane col decomposition, byte-packed (kh,kw <= 13): saves ~18 VGPR
  unsigned ckhp[4] = {0, 0, 0, 0}, ckwp[4] = {0, 0, 0, 0};
#pragma unroll
  for (int f = 0; f < 13; f++) {
    int col = f * 16 + lc; if (col > 195) col = 195;
    int kh = col / 14, kw = col - kh * 14;
    ckhp[f >> 2] |= (unsigned)kh << ((f & 3) * 8);
    ckwp[f >> 2] |= (unsigned)kw << ((f & 3) * 8);
  }

  const v8s* TBv = (const v8s*)TB;
  const v4i vz = {0, 0, 0, 0};

  // ---- rel-pos bias via bf16 MFMA ----
  {
    int arow = t * 16 + lc; if (arow > 195) arow = 195;
    const i8* qrow = qq + ((size_t)bh * 196 + arow) * 64;
    v8s af[2];
#pragma unroll
    for (int ks = 0; ks < 2; ks++) {
      const i8* p = qrow + ks * 32 + quad * 8;
#pragma unroll
      for (int j = 0; j < 8; j++)
        af[ks][j] = (short)(__float_as_uint((float)p[j]) >> 16);  // exact int->bf16
    }
    v4f rh0 = {0,0,0,0}, rh1 = {0,0,0,0}, rw0 = {0,0,0,0}, rw1 = {0,0,0,0};
#pragma unroll
    for (int ks = 0; ks < 2; ks++)
#pragma unroll
      for (int p2 = 0; p2 < 2; p2++) {
        rh0 = __builtin_amdgcn_mfma_f32_16x16x32_bf16(af[ks], TBv[(0*4 + ks*2 + p2)*64 + lane], rh0, 0, 0, 0);
        rh1 = __builtin_amdgcn_mfma_f32_16x16x32_bf16(af[ks], TBv[(1*4 + ks*2 + p2)*64 + lane], rh1, 0, 0, 0);
        rw0 = __builtin_amdgcn_mfma_f32_16x16x32_bf16(af[ks], TBv[(2*4 + ks*2 + p2)*64 + lane], rw0, 0, 0, 0);
        rw1 = __builtin_amdgcn_mfma_f32_16x16x32_bf16(af[ks], TBv[(3*4 + ks*2 + p2)*64 + lane], rw1, 0, 0, 0);
      }
#pragma unroll
    for (int r = 0; r < 4; r++) {
      int rl = quad * 4 + r;
      relS[rl][lc]      = rh0[r] * s0;
      relS[rl][16 + lc] = rh1[r] * s0;
      relS[rl][32 + lc] = rw0[r] * s0;
      relS[rl][48 + lc] = rw1[r] * s0;
    }
  }

  // ---- QK^T (int-exact) ----
  v4i aq = *(const v4i*)(qq + ((size_t)bh * 196 + t * 16 + lc) * 64 + quad * 16);
  v4i sacc[13];
#pragma unroll
  for (int f = 0; f < 13; f++) {
    v4i bk = *(const v4i*)(kq + ((size_t)bh * 196 + f * 16 + lc) * 64 + quad * 16);
    sacc[f] = __builtin_amdgcn_mfma_i32_16x16x64_i8(aq, bk, vz, 0, 0, 0);
  }

  // ---- softmax + P quant ----
#pragma unroll
  for (int r = 0; r < 4; r++) {
    int rl = quad * 4 + r;
    int row = t * 16 + rl;
    int qh = row / 14, qw = row - qh * 14;
    const float* rH = &relS[rl][13 + qh];        // rH[-kh]
    const float* rW = &relS[rl][32 + 13 + qw];   // rW[-kw]
    float L[13];
#pragma unroll
    for (int f = 0; f < 13; f++) {
      int kh = (int)((ckhp[f >> 2] >> ((f & 3) * 8)) & 0xffu);
      int kw = (int)((ckwp[f >> 2] >> ((f & 3) * 8)) & 0xffu);
      // cok = col<196  <=>  f<12 || lc<4  (compile-time for f<12 under unroll)
      L[f] = ((f < 12) | (lc < 4)) ? fmaf((float)sacc[f][r], ssc, rH[-kh] + rW[-kw]) : -1e30f;
    }
    float mx = L[0];
#pragma unroll
    for (int f = 1; f < 13; f++) mx = fmaxf(mx, L[f]);
#pragma unroll
    for (int off = 1; off < 16; off <<= 1) mx = fmaxf(mx, __shfl_xor(mx, off));
    float sum = 0.f;
#pragma unroll
    for (int f = 0; f < 13; f++) { float e = __expf(L[f] - mx); L[f] = e; sum += e; }
#pragma unroll
    for (int off = 1; off < 16; off <<= 1) sum += __shfl_xor(sum, off);
    float cq = (1.0f / sum) * invs3;
#pragma unroll
    for (int f = 0; f < 13; f++)
      Ps[rl * 272 + f * 16 + lc] = satq(L[f] * cq);
  }

  // ---- PV (int-exact) ----
  v4i oacc[4];
#pragma unroll
  for (int nt = 0; nt < 4; nt++) oacc[nt] = vz;
#pragma unroll
  for (int kc = 0; kc < 4; kc++) {
    v4i ap = *(const v4i*)(Ps + lc * 272 + kc * 64 + quad * 16);
#pragma unroll
    for (int nt = 0; nt < 4; nt++) {
      v4i bv = *(const v4i*)(vt + ((size_t)bh * 64 + nt * 16 + lc) * 256 + kc * 64 + quad * 16);
      oacc[nt] = __builtin_amdgcn_mfma_i32_16x16x64_i8(ap, bv, oacc[nt], 0, 0, 0);
    }
  }
#pragma unroll
  for (int nt = 0; nt < 4; nt++) {
    int ch = nt * 16 + lc;
#pragma unroll
    for (int r = 0; r < 4; r++) {
      int row = t * 16 + quad * 4 + r;
      if (row < 196)
        outq[((size_t)win * 196 + row) * 768 + head * 64 + ch] = satq((float)oacc[nt][r] * oscale);
    }
  }
}

// ---------------------------------------------------------------------------
extern "C" void kernel_launch(void* const* d_in, const int* in_sizes, int n_in,
                              void* d_out, int out_size, void* d_ws, size_t ws_size,
                              hipStream_t stream) {
  const float* x     = (const float*)d_in[0];
  const float* ln1w  = (const float*)d_in[1];
  const float* ln1b  = (const float*)d_in[2];
  const float* ln2w  = (const float*)d_in[3];
  const float* ln2b  = (const float*)d_in[4];
  const float* qkvw  = (const float*)d_in[5];
  const float* qkvb  = (const float*)d_in[6];
  const float* projw = (const float*)d_in[7];
  const float* projb = (const float*)d_in[8];
  const float* lin1w = (const float*)d_in[9];
  const float* lin1b = (const float*)d_in[10];
  const float* lin2w = (const float*)d_in[11];
  const float* lin2b = (const float*)d_in[12];
  const float* rph   = (const float*)d_in[13];
  const float* rpw   = (const float*)d_in[14];
  const float* as    = (const float*)d_in[15];
  const float* wsc   = (const float*)d_in[16];
  float* out = (float*)d_out;

  // ws layout (72,462,336 B total), regions reused across stages:
  char* ws = (char*)d_ws;
  i8* big    = (i8*)ws;                          // 50,331,648
  i8* qq     = big;                              // 15,052,800 (1200*196*64)
  i8* kq     = big + 15052800;                   // 15,052,800
  i8* vt     = big + 30105600;                   // 19,660,800 (1200*64*256)
  short* TB  = (short*)(big + 49766400);         //     16,384 (rel tables; dead before lin1)
  i8* mlpq   = big;                              // 50,331,648 (16384*3072), after attn
  i8* creg   = (i8*)(ws + 50331648);             // 15,052,800
  i8* winq   = creg;                             // qkv input
  i8* attno  = creg;                             // proj input (after qkv dead)
  i8* yq     = creg;                             // lin1 input (after proj dead)
  i8* wqb    = (i8*)(ws + 65384448);             //  7,077,888
  i8* qkvwq  = wqb;
  i8* projwq = wqb + 1769472;
  i8* lin1wq = projwq + 589824;
  i8* lin2wq = lin1wq + 2359296;

  k_wquant<<<(110592 + 255) / 256, 256, 0, stream>>>(qkvw,  qkvwq,  110592, wsc, 0);
  k_wquant<<<( 36864 + 255) / 256, 256, 0, stream>>>(projw, projwq,  36864, wsc, 1);
  k_wquant<<<(147456 + 255) / 256, 256, 0, stream>>>(lin1w, lin1wq, 147456, wsc, 2);
  k_wquant<<<(147456 + 255) / 256, 256, 0, stream>>>(lin2w, lin2wq, 147456, wsc, 3);
  k_relpack<<<4, 256, 0, stream>>>(rph, rpw, TB);

  k_ln1<<<4900, 256, 0, stream>>>(x, ln1w, ln1b, as, winq);

  { EpiQKV e{as, wsc, qkvb, qq, kq, vt};
    k_gemm<EpiQKV><<<dim3(18, 154), 256, 0, stream>>>(winq, qkvwq, 19600, 2304, 768, e); }

  k_attn<<<dim3(13, 1200), 64, 0, stream>>>(qq, kq, vt, TB, as, attno);

  { EpiProj e{as, wsc, projb, x, out};
    k_gemm<EpiProj><<<dim3(6, 154), 256, 0, stream>>>(attno, projwq, 19600, 768, 768, e); }

  k_ln2<<<4096, 256, 0, stream>>>(out, ln2w, ln2b, as, yq);

  { EpiLin1 e{as, wsc, lin1b, mlpq};
    k_gemm<EpiLin1><<<dim3(24, 128), 256, 0, stream>>>(yq, lin1wq, 16384, 3072, 768, e); }

  { EpiLin2 e{as, wsc, lin2b, out};
    k_gemm<EpiLin2><<<dim3(6, 128), 256, 0, stream>>>(mlpq, lin2wq, 16384, 768, 3072, e); }
}